// Round 1
// baseline (846.517 us; speedup 1.0000x reference)
//
#include <hip/hip_runtime.h>

#define BATCH   16
#define NCGS    256
#define NATOMS  1024
#define KNN     32
#define KF      128
#define DEPTHN  3

#define CGS_PER_BLOCK 4
#define ROWS    128           // CGS_PER_BLOCK * KNN
#define FSTRIDE 132           // padded row stride (floats), 16B aligned

__device__ __forceinline__ float4 ld4(const float* p) { return *(const float4*)p; }

// ---------------------------------------------------------------------------
// Fused edge-MLP: RBF features -> 3x(mlp,mean,upd) -> dec_W1+relu -> G partials
// grid = BATCH * 64 blocks (4 cgs each), 256 threads
// ---------------------------------------------------------------------------
__global__ __launch_bounds__(256)
void mlp_kernel(const float* __restrict__ cg_xyz,
                const float* __restrict__ mlp_W1, const float* __restrict__ mlp_b1,
                const float* __restrict__ mlp_W2, const float* __restrict__ mlp_b2,
                const float* __restrict__ upd_W1, const float* __restrict__ upd_b1,
                const float* __restrict__ upd_W2, const float* __restrict__ upd_b2,
                const float* __restrict__ dec_W1, const float* __restrict__ dec_b1,
                float* __restrict__ G)           // [BATCH][KF][3], pre-zeroed
{
    __shared__ float Fin[ROWS * FSTRIDE];        // 67.6 KB
    __shared__ float Wlds[KF * KF];              // 64 KB
    __shared__ float dvec[ROWS * 3];
    __shared__ float dist[ROWS];
    __shared__ float meanb[CGS_PER_BLOCK * KF];

    const int tid = threadIdx.x;
    const int b   = blockIdx.x >> 6;
    const int cg0 = (blockIdx.x & 63) * CGS_PER_BLOCK;

    // ---- setup: dist_vec / dist for this block's 128 edges ----
    if (tid < ROWS) {
        int r  = tid;
        int c  = cg0 + (r >> 5);
        int nb = 1 + (r & 31);
        const float* cgb = cg_xyz + (size_t)b * NCGS * 3;
        float dx = cgb[nb*3+0] - cgb[c*3+0];
        float dy = cgb[nb*3+1] - cgb[c*3+1];
        float dz = cgb[nb*3+2] - cgb[c*3+2];
        dvec[r*3+0] = dx; dvec[r*3+1] = dy; dvec[r*3+2] = dz;
        dist[r] = sqrtf(dx*dx + dy*dy + dz*dz);
    }
    __syncthreads();

    // ---- RBF features ----
    const float STEP  = 10.0f / 127.0f;
    const float COEFF = -0.5f / (STEP * STEP);
    for (int idx = tid; idx < ROWS * KF; idx += 256) {
        int r = idx >> 7, k = idx & 127;
        float t = dist[r] - (float)k * STEP;
        Fin[r * FSTRIDE + k] = expf(COEFF * t * t);
    }

    const int o0 = (tid & 15) * 8;   // output-column tile
    const int j0 = (tid >> 4) * 8;   // row tile

    // ---- 13 GEMM steps ----
    for (int s = 0; s < 13; ++s) {
        const float *W, *bias;
        int md;                       // 0 = relu, 1 = bias-only + mean-add, 2 = plain
        if (s < 12) {
            int d = s >> 2, ph = s & 3;
            if      (ph == 0) { W = mlp_W1 + d*KF*KF; bias = mlp_b1 + d*KF; md = 0; }
            else if (ph == 1) { W = mlp_W2 + d*KF*KF; bias = mlp_b2 + d*KF; md = 1; }
            else if (ph == 2) { W = upd_W1 + d*KF*KF; bias = upd_b1 + d*KF; md = 0; }
            else              { W = upd_W2 + d*KF*KF; bias = upd_b2 + d*KF; md = 2; }
        } else { W = dec_W1; bias = dec_b1; md = 0; }

        __syncthreads();             // prev Fin writes visible; prev W reads done
        {   // stage W into LDS (coalesced float4)
            const float4* Wg = (const float4*)W;
            float4*       Wl = (float4*)Wlds;
            #pragma unroll
            for (int i = 0; i < 16; ++i) Wl[tid + i*256] = Wg[tid + i*256];
        }
        __syncthreads();

        float bb[8];
        {   float4 b0 = ld4(bias + o0), b1v = ld4(bias + o0 + 4);
            bb[0]=b0.x; bb[1]=b0.y; bb[2]=b0.z; bb[3]=b0.w;
            bb[4]=b1v.x; bb[5]=b1v.y; bb[6]=b1v.z; bb[7]=b1v.w; }

        float acc[8][8];
        #pragma unroll
        for (int i = 0; i < 8; ++i)
            #pragma unroll
            for (int j = 0; j < 8; ++j) acc[i][j] = 0.f;

        #pragma unroll 4
        for (int k = 0; k < KF; ++k) {
            float a[8];
            #pragma unroll
            for (int i = 0; i < 8; ++i) a[i] = Fin[(j0 + i) * FSTRIDE + k];
            float4 w0 = *(const float4*)&Wlds[k*KF + o0];
            float4 w1 = *(const float4*)&Wlds[k*KF + o0 + 4];
            float w[8] = {w0.x,w0.y,w0.z,w0.w,w1.x,w1.y,w1.z,w1.w};
            #pragma unroll
            for (int i = 0; i < 8; ++i)
                #pragma unroll
                for (int j = 0; j < 8; ++j)
                    acc[i][j] = fmaf(a[i], w[j], acc[i][j]);
        }
        __syncthreads();             // all Fin reads done before overwrite

        #pragma unroll
        for (int i = 0; i < 8; ++i) {
            #pragma unroll
            for (int j = 0; j < 8; ++j) {
                float v = acc[i][j] + bb[j];
                if (md == 0) v = fmaxf(v, 0.f);
                acc[i][j] = v;
            }
            *(float4*)&Fin[(j0+i)*FSTRIDE + o0]     = make_float4(acc[i][0],acc[i][1],acc[i][2],acc[i][3]);
            *(float4*)&Fin[(j0+i)*FSTRIDE + o0 + 4] = make_float4(acc[i][4],acc[i][5],acc[i][6],acc[i][7]);
        }

        if (md == 1) {               // h = upd + mean_over_knn(upd)
            __syncthreads();
            for (int idx = tid; idx < CGS_PER_BLOCK * KF; idx += 256) {
                int c = idx >> 7, k = idx & 127;
                float ssum = 0.f;
                #pragma unroll 8
                for (int r = 0; r < KNN; ++r) ssum += Fin[(c*KNN + r)*FSTRIDE + k];
                meanb[idx] = ssum * (1.f / KNN);
            }
            __syncthreads();
            for (int idx = tid; idx < ROWS * KF; idx += 256) {
                int r = idx >> 7, k = idx & 127;
                Fin[r*FSTRIDE + k] += meanb[(r >> 5)*KF + k];
            }
        }
    }
    __syncthreads();

    // ---- G partials: G[b,k,n] += sum_r R[r,k] * dvec[r,n] ----
    if (tid < KF) {
        int k = tid;
        float g0 = 0.f, g1 = 0.f, g2 = 0.f;
        #pragma unroll 4
        for (int r = 0; r < ROWS; ++r) {
            float rv = Fin[r*FSTRIDE + k];
            g0 = fmaf(rv, dvec[r*3+0], g0);
            g1 = fmaf(rv, dvec[r*3+1], g1);
            g2 = fmaf(rv, dvec[r*3+2], g2);
        }
        float* Gb = G + ((size_t)b * KF + k) * 3;
        atomicAdd(Gb+0, g0); atomicAdd(Gb+1, g1); atomicAdd(Gb+2, g2);
    }
}

// ---------------------------------------------------------------------------
// dx_recon[b,o,n] = sum_k dec_W2[k,o]*G[b,k,n] + dec_b2[o]*S[b,n]
// S computed in closed form from cg_xyz. grid = BATCH*4, 256 threads (1 o each)
// ---------------------------------------------------------------------------
__global__ __launch_bounds__(256)
void dx_kernel(const float* __restrict__ cg_xyz, const float* __restrict__ dec_W2,
               const float* __restrict__ dec_b2, const float* __restrict__ G,
               float* __restrict__ dxr)
{
    __shared__ float Gl[KF * 3];
    __shared__ float red[256 * 3];
    const int tid = threadIdx.x;
    const int b   = blockIdx.x >> 2;
    const int og  = blockIdx.x & 3;

    if (tid < 192) {
        Gl[tid]       = G[(size_t)b*KF*3 + tid];
        Gl[tid + 192] = G[(size_t)b*KF*3 + tid + 192];
    }
    // S[b,n] = 256*sum_{j=1..32} cg[j] - 32*sum_{i} cg[i]
    const float* cgb = cg_xyz + (size_t)b * NCGS * 3;
    float w = ((tid >= 1 && tid <= 32) ? 256.f : 0.f) - 32.f;
    red[tid]       = w * cgb[tid*3+0];
    red[256 + tid] = w * cgb[tid*3+1];
    red[512 + tid] = w * cgb[tid*3+2];
    __syncthreads();
    for (int s2 = 128; s2 > 0; s2 >>= 1) {
        if (tid < s2) {
            red[tid]       += red[tid + s2];
            red[256 + tid] += red[256 + tid + s2];
            red[512 + tid] += red[512 + tid + s2];
        }
        __syncthreads();
    }
    const float S0 = red[0], S1 = red[256], S2 = red[512];

    const int o = og * 256 + tid;
    const float bq = dec_b2[o];
    float a0 = bq * S0, a1 = bq * S1, a2 = bq * S2;
    #pragma unroll 4
    for (int k = 0; k < KF; ++k) {
        float wv = dec_W2[k * NATOMS + o];
        a0 = fmaf(wv, Gl[k*3+0], a0);
        a1 = fmaf(wv, Gl[k*3+1], a1);
        a2 = fmaf(wv, Gl[k*3+2], a2);
    }
    float* dp = dxr + ((size_t)b * NATOMS + o) * 3;
    dp[0] = a0; dp[1] = a1; dp[2] = a2;
}

// ---------------------------------------------------------------------------
// cg_offset[b,j,n] = sum_a dx[b,a,n]*assign_norm[b,a,j]
// grid = BATCH*16 (64 atoms each), 256 threads (1 j each), atomic accumulate
// ---------------------------------------------------------------------------
__global__ __launch_bounds__(256)
void cgo_kernel(const float* __restrict__ assign_norm, const float* __restrict__ dxr,
                float* __restrict__ cgo)
{
    __shared__ float dxl[64 * 3];
    const int tid = threadIdx.x;
    const int b   = blockIdx.x >> 4;
    const int a0  = (blockIdx.x & 15) * 64;
    if (tid < 192) dxl[tid] = dxr[((size_t)b * NATOMS + a0) * 3 + tid];
    __syncthreads();
    float c0 = 0.f, c1 = 0.f, c2 = 0.f;
    const float* an = assign_norm + ((size_t)b * NATOMS + a0) * NCGS + tid;
    #pragma unroll 4
    for (int a = 0; a < 64; ++a) {
        float v = an[(size_t)a * NCGS];
        c0 = fmaf(v, dxl[a*3+0], c0);
        c1 = fmaf(v, dxl[a*3+1], c1);
        c2 = fmaf(v, dxl[a*3+2], c2);
    }
    float* cp = cgo + ((size_t)b * NCGS + tid) * 3;
    atomicAdd(cp+0, c0); atomicAdd(cp+1, c1); atomicAdd(cp+2, c2);
}

// ---------------------------------------------------------------------------
// xyz_recon = cg_xyz[idx] - cgo[idx] + dx ; grid = 192, 256 threads
// ---------------------------------------------------------------------------
__global__ __launch_bounds__(256)
void recon_kernel(const float* __restrict__ cg_xyz, const float* __restrict__ cgo,
                  const float* __restrict__ dxr, const int* __restrict__ assign_idx,
                  float* __restrict__ out)
{
    int i = blockIdx.x * 256 + threadIdx.x;            // < BATCH*NATOMS*3
    int b   = i / (NATOMS * 3);
    int rem = i - b * (NATOMS * 3);
    int a   = rem / 3;
    int n   = rem - a * 3;
    int ia  = assign_idx[a];
    float v = cg_xyz[((size_t)b*NCGS + ia)*3 + n]
            - cgo[((size_t)b*NCGS + ia)*3 + n]
            + dxr[((size_t)b*NATOMS + a)*3 + n];
    out[i] = v;
}

// ---------------------------------------------------------------------------
extern "C" void kernel_launch(void* const* d_in, const int* in_sizes, int n_in,
                              void* d_out, int out_size, void* d_ws, size_t ws_size,
                              hipStream_t stream)
{
    const float* soft_assign = (const float*)d_in[0];
    const float* xyz         = (const float*)d_in[1];
    const float* cg_xyz      = (const float*)d_in[2];
    const float* assign_norm = (const float*)d_in[3];
    const int*   assign_idx  = (const int*)  d_in[4];
    const float* mlp_W1 = (const float*)d_in[5];
    const float* mlp_b1 = (const float*)d_in[6];
    const float* mlp_W2 = (const float*)d_in[7];
    const float* mlp_b2 = (const float*)d_in[8];
    const float* upd_W1 = (const float*)d_in[9];
    const float* upd_b1 = (const float*)d_in[10];
    const float* upd_W2 = (const float*)d_in[11];
    const float* upd_b2 = (const float*)d_in[12];
    const float* dec_W1 = (const float*)d_in[13];
    const float* dec_b1 = (const float*)d_in[14];
    const float* dec_W2 = (const float*)d_in[15];
    const float* dec_b2 = (const float*)d_in[16];

    float* out = (float*)d_out;

    // workspace layout (floats): G[16*128*3] | cgo[16*256*3] | dxr[16*1024*3]
    float* G   = (float*)d_ws;
    float* cgo = G + BATCH * KF * 3;
    float* dxr = cgo + BATCH * NCGS * 3;

    // passthrough outputs
    hipMemcpyAsync(out, soft_assign, (size_t)BATCH*NATOMS*NCGS*sizeof(float),
                   hipMemcpyDeviceToDevice, stream);
    hipMemcpyAsync(out + (size_t)BATCH*NATOMS*NCGS, xyz,
                   (size_t)BATCH*NATOMS*3*sizeof(float),
                   hipMemcpyDeviceToDevice, stream);
    // zero atomic accumulators (G and cgo)
    hipMemsetAsync(G, 0, (size_t)(BATCH*KF*3 + BATCH*NCGS*3)*sizeof(float), stream);

    mlp_kernel<<<BATCH*64, 256, 0, stream>>>(cg_xyz,
        mlp_W1, mlp_b1, mlp_W2, mlp_b2, upd_W1, upd_b1, upd_W2, upd_b2,
        dec_W1, dec_b1, G);
    dx_kernel<<<BATCH*4, 256, 0, stream>>>(cg_xyz, dec_W2, dec_b2, G, dxr);
    cgo_kernel<<<BATCH*16, 256, 0, stream>>>(assign_norm, dxr, cgo);
    recon_kernel<<<(BATCH*NATOMS*3)/256, 256, 0, stream>>>(
        cg_xyz, cgo, dxr, assign_idx,
        out + (size_t)BATCH*NATOMS*NCGS + (size_t)BATCH*NATOMS*3);
}

// Round 2
// 341.736 us; speedup vs baseline: 2.4771x; 2.4771x over previous
//
#include <hip/hip_runtime.h>

#define BATCH   16
#define NCGS    256
#define NATOMS  1024
#define KNN     32
#define KF      128

typedef __attribute__((ext_vector_type(8))) short bf16x8;
typedef __attribute__((ext_vector_type(4))) float f32x4;

#define NFRAG (13*8*4)              // step*ft*kc fragments
// Wswz layout: [fi][plane][lane] 16B each; fi = (s*8+ft)*4+kc

// ---------------------------------------------------------------------------
// Weight pre-swizzle: W_s[k][f] -> A-fragment order (A[m=f][k]), bf16 hi/lo.
// grid = 104 x 256 threads; one thread = one (s,ft,kc,lane) fragment pair.
// ---------------------------------------------------------------------------
__global__ __launch_bounds__(256)
void prep_kernel(const float* __restrict__ mlp_W1, const float* __restrict__ mlp_W2,
                 const float* __restrict__ upd_W1, const float* __restrict__ upd_W2,
                 const float* __restrict__ dec_W1, uint* __restrict__ Wswz)
{
    int t = blockIdx.x * 256 + threadIdx.x;
    if (t >= 13*8*4*64) return;
    int lane = t & 63;
    int kc   = (t >> 6) & 3;
    int ft   = (t >> 8) & 7;
    int s    = t >> 11;

    const float* W;
    if (s < 12) {
        int d = s >> 2, ph = s & 3;
        if      (ph == 0) W = mlp_W1 + d*KF*KF;
        else if (ph == 1) W = mlp_W2 + d*KF*KF;
        else if (ph == 2) W = upd_W1 + d*KF*KF;
        else              W = upd_W2 + d*KF*KF;
    } else W = dec_W1;

    int f  = ft*16 + (lane & 15);
    int kb = kc*32 + (lane >> 4)*8;

    uint hi[4], lo[4];
    #pragma unroll
    for (int w = 0; w < 4; ++w) {
        float v0 = W[(kb + 2*w    )*KF + f];
        float v1 = W[(kb + 2*w + 1)*KF + f];
        uint b0 = __float_as_uint(v0), b1 = __float_as_uint(v1);
        hi[w] = (b0 >> 16) | (b1 & 0xffff0000u);
        float l0 = v0 - __uint_as_float(b0 & 0xffff0000u);
        float l1 = v1 - __uint_as_float(b1 & 0xffff0000u);
        lo[w] = (__float_as_uint(l0) >> 16) | (__float_as_uint(l1) & 0xffff0000u);
    }
    int fi = (s*8 + ft)*4 + kc;
    uint* ph_ = Wswz + (size_t)((fi*2 + 0)*64 + lane)*4;
    uint* pl_ = Wswz + (size_t)((fi*2 + 1)*64 + lane)*4;
    #pragma unroll
    for (int w = 0; w < 4; ++w) { ph_[w] = hi[w]; pl_[w] = lo[w]; }
}

// ---------------------------------------------------------------------------
// Fused MFMA edge-MLP. grid = BATCH*64 (4 cgs / block), 256 threads (4 waves).
// Wave w owns cg (cg0+w): rows [32w,32w+32). No __syncthreads until G.
// ---------------------------------------------------------------------------
__global__ __launch_bounds__(256, 2)
void mlp_kernel(const float* __restrict__ cg_xyz, const bf16x8* __restrict__ Wf,
                const float* __restrict__ mlp_b1, const float* __restrict__ mlp_b2,
                const float* __restrict__ upd_b1, const float* __restrict__ upd_b2,
                const float* __restrict__ dec_b1, float* __restrict__ G)
{
    __shared__ __align__(16) short Fs[2][KF*KF];   // hi, lo planes (64 KB)
    __shared__ float dvec[128*3];

    const int tid = threadIdx.x;
    const int wv  = tid >> 6;
    const int l   = tid & 63;
    const int b   = blockIdx.x >> 6;
    const int cg0 = (blockIdx.x & 63) * 4;
    const int cg  = cg0 + wv;

    char* hB = (char*)&Fs[0][0];
    char* lB = (char*)&Fs[1][0];

    // ---- per-lane dvec / dist (lanes 32-63 duplicate 0-31) ----
    const float* cgb = cg_xyz + (size_t)b * NCGS * 3;
    const int rl = l & 31;
    const int nb = 1 + rl;
    float dxv = cgb[nb*3+0] - cgb[cg*3+0];
    float dyv = cgb[nb*3+1] - cgb[cg*3+1];
    float dzv = cgb[nb*3+2] - cgb[cg*3+2];
    float dist = sqrtf(dxv*dxv + dyv*dyv + dzv*dzv);
    if (l < 32) {
        int r = wv*32 + rl;
        dvec[r*3+0] = dxv; dvec[r*3+1] = dyv; dvec[r*3+2] = dzv;
    }

    // ---- RBF features into swizzled hi/lo LDS (own rows only) ----
    {
        const float STEP  = 10.0f / 127.0f;
        const float COEFF = -0.5f / (STEP * STEP);
        int r  = wv*32 + rl;
        int kh = (l >> 5) * 64;
        uint rb = (uint)r * 256;
        uint sw = (uint)(r & 7) << 4;
        #pragma unroll 8
        for (int j = 0; j < 32; ++j) {
            int k = kh + 2*j;
            float t0 = dist - (float)k * STEP;
            float t1 = dist - (float)(k+1) * STEP;
            float e0 = expf(COEFF * t0 * t0);
            float e1 = expf(COEFF * t1 * t1);
            uint b0 = __float_as_uint(e0), b1 = __float_as_uint(e1);
            uint hw = (b0 >> 16) | (b1 & 0xffff0000u);
            float l0 = e0 - __uint_as_float(b0 & 0xffff0000u);
            float l1 = e1 - __uint_as_float(b1 & 0xffff0000u);
            uint lw = (__float_as_uint(l0) >> 16) | (__float_as_uint(l1) & 0xffff0000u);
            uint off = rb + (((uint)(2*k)) ^ sw);
            *(uint*)(hB + off) = hw;
            *(uint*)(lB + off) = lw;
        }
    }

    // ---- 13 MFMA GEMM steps, wave-private ----
    for (int s = 0; s < 13; ++s) {
        const float* bias; int md;
        if (s < 12) {
            int d = s >> 2, ph = s & 3;
            if      (ph == 0) { bias = mlp_b1 + d*KF; md = 0; }
            else if (ph == 1) { bias = mlp_b2 + d*KF; md = 1; }
            else if (ph == 2) { bias = upd_b1 + d*KF; md = 0; }
            else              { bias = upd_b2 + d*KF; md = 2; }
        } else { bias = dec_b1; md = 0; }

        // load B-fragments of own F rows: [rt][kc][plane]
        bf16x8 bf[2][4][2];
        #pragma unroll
        for (int rt = 0; rt < 2; ++rt) {
            int r = wv*32 + rt*16 + (l & 15);
            uint rb = (uint)r * 256;
            uint sw = (uint)(r & 7) << 4;
            #pragma unroll
            for (int kc = 0; kc < 4; ++kc) {
                uint cb = (uint)(kc*64 + ((l >> 4) << 4));
                uint off = rb + (cb ^ sw);
                bf[rt][kc][0] = *(const bf16x8*)(hB + off);
                bf[rt][kc][1] = *(const bf16x8*)(lB + off);
            }
        }

        f32x4 acc[8][2];
        #pragma unroll
        for (int ft = 0; ft < 8; ++ft)
            #pragma unroll
            for (int rt = 0; rt < 2; ++rt)
                acc[ft][rt] = (f32x4){0.f, 0.f, 0.f, 0.f};

        #pragma unroll
        for (int kc = 0; kc < 4; ++kc) {
            #pragma unroll
            for (int ft = 0; ft < 8; ++ft) {
                int fi = (s*8 + ft)*4 + kc;
                bf16x8 whi = Wf[(fi*2 + 0)*64 + l];
                bf16x8 wlo = Wf[(fi*2 + 1)*64 + l];
                #pragma unroll
                for (int rt = 0; rt < 2; ++rt) {
                    acc[ft][rt] = __builtin_amdgcn_mfma_f32_16x16x32_bf16(whi, bf[rt][kc][0], acc[ft][rt], 0, 0, 0);
                    acc[ft][rt] = __builtin_amdgcn_mfma_f32_16x16x32_bf16(whi, bf[rt][kc][1], acc[ft][rt], 0, 0, 0);
                    acc[ft][rt] = __builtin_amdgcn_mfma_f32_16x16x32_bf16(wlo, bf[rt][kc][0], acc[ft][rt], 0, 0, 0);
                }
            }
        }

        // epilogue: bias (+relu | +mean | plain), convert hi/lo, write back
        #pragma unroll
        for (int ft = 0; ft < 8; ++ft) {
            float4 bv = *(const float4*)(bias + ft*16 + ((l >> 4) << 2));
            #pragma unroll
            for (int rt = 0; rt < 2; ++rt) {
                acc[ft][rt][0] += bv.x; acc[ft][rt][1] += bv.y;
                acc[ft][rt][2] += bv.z; acc[ft][rt][3] += bv.w;
            }
        }
        if (md == 0) {
            #pragma unroll
            for (int ft = 0; ft < 8; ++ft)
                #pragma unroll
                for (int rt = 0; rt < 2; ++rt)
                    #pragma unroll
                    for (int q = 0; q < 4; ++q)
                        acc[ft][rt][q] = fmaxf(acc[ft][rt][q], 0.f);
        } else if (md == 1) {
            // h = upd + mean over the 32 knn rows (wave-internal)
            #pragma unroll
            for (int ft = 0; ft < 8; ++ft)
                #pragma unroll
                for (int q = 0; q < 4; ++q) {
                    float sm = acc[ft][0][q] + acc[ft][1][q];
                    sm += __shfl_xor(sm, 1);
                    sm += __shfl_xor(sm, 2);
                    sm += __shfl_xor(sm, 4);
                    sm += __shfl_xor(sm, 8);
                    float mn = sm * (1.0f / 32.0f);
                    acc[ft][0][q] += mn;
                    acc[ft][1][q] += mn;
                }
        }
        #pragma unroll
        for (int ft = 0; ft < 8; ++ft) {
            #pragma unroll
            for (int rt = 0; rt < 2; ++rt) {
                int r = wv*32 + rt*16 + (l & 15);
                uint sw  = (uint)(r & 7) << 4;
                uint off = (uint)r*256 + (((uint)(ft*32 + ((l >> 4) << 3))) ^ sw);
                uint b0 = __float_as_uint(acc[ft][rt][0]);
                uint b1 = __float_as_uint(acc[ft][rt][1]);
                uint b2 = __float_as_uint(acc[ft][rt][2]);
                uint b3 = __float_as_uint(acc[ft][rt][3]);
                uint2 hw, lw;
                hw.x = (b0 >> 16) | (b1 & 0xffff0000u);
                hw.y = (b2 >> 16) | (b3 & 0xffff0000u);
                float l0 = acc[ft][rt][0] - __uint_as_float(b0 & 0xffff0000u);
                float l1 = acc[ft][rt][1] - __uint_as_float(b1 & 0xffff0000u);
                float l2 = acc[ft][rt][2] - __uint_as_float(b2 & 0xffff0000u);
                float l3 = acc[ft][rt][3] - __uint_as_float(b3 & 0xffff0000u);
                lw.x = (__float_as_uint(l0) >> 16) | (__float_as_uint(l1) & 0xffff0000u);
                lw.y = (__float_as_uint(l2) >> 16) | (__float_as_uint(l3) & 0xffff0000u);
                *(uint2*)(hB + off) = hw;
                *(uint2*)(lB + off) = lw;
            }
        }
    }
    __syncthreads();

    // ---- G[b,k,n] += sum_r R[r,k] * dvec[r,n] ----
    {
        int k  = tid & 127;
        int rh = tid >> 7;
        float g0 = 0.f, g1 = 0.f, g2 = 0.f;
        #pragma unroll 4
        for (int rr = 0; rr < 64; ++rr) {
            int r = rh*64 + rr;
            uint off = (uint)r*256 + (((uint)(2*k)) ^ ((uint)(r & 7) << 4));
            uint hv = *(unsigned short*)(hB + off);
            uint lv = *(unsigned short*)(lB + off);
            float v = __uint_as_float(hv << 16) + __uint_as_float(lv << 16);
            g0 = fmaf(v, dvec[r*3+0], g0);
            g1 = fmaf(v, dvec[r*3+1], g1);
            g2 = fmaf(v, dvec[r*3+2], g2);
        }
        float* Gb = G + ((size_t)b * KF + k) * 3;
        atomicAdd(Gb+0, g0); atomicAdd(Gb+1, g1); atomicAdd(Gb+2, g2);
    }
}

// ---------------------------------------------------------------------------
// dx_recon[b,o,n] = sum_k dec_W2[k,o]*G[b,k,n] + dec_b2[o]*S[b,n]
// ---------------------------------------------------------------------------
__global__ __launch_bounds__(256)
void dx_kernel(const float* __restrict__ cg_xyz, const float* __restrict__ dec_W2,
               const float* __restrict__ dec_b2, const float* __restrict__ G,
               float* __restrict__ dxr)
{
    __shared__ float Gl[KF * 3];
    __shared__ float red[256 * 3];
    const int tid = threadIdx.x;
    const int b   = blockIdx.x >> 2;
    const int og  = blockIdx.x & 3;

    if (tid < 192) {
        Gl[tid]       = G[(size_t)b*KF*3 + tid];
        Gl[tid + 192] = G[(size_t)b*KF*3 + tid + 192];
    }
    const float* cgb = cg_xyz + (size_t)b * NCGS * 3;
    float w = ((tid >= 1 && tid <= 32) ? 256.f : 0.f) - 32.f;
    red[tid]       = w * cgb[tid*3+0];
    red[256 + tid] = w * cgb[tid*3+1];
    red[512 + tid] = w * cgb[tid*3+2];
    __syncthreads();
    for (int s2 = 128; s2 > 0; s2 >>= 1) {
        if (tid < s2) {
            red[tid]       += red[tid + s2];
            red[256 + tid] += red[256 + tid + s2];
            red[512 + tid] += red[512 + tid + s2];
        }
        __syncthreads();
    }
    const float S0 = red[0], S1 = red[256], S2 = red[512];

    const int o = og * 256 + tid;
    const float bq = dec_b2[o];
    float a0 = bq * S0, a1 = bq * S1, a2 = bq * S2;
    #pragma unroll 4
    for (int k = 0; k < KF; ++k) {
        float wvv = dec_W2[k * NATOMS + o];
        a0 = fmaf(wvv, Gl[k*3+0], a0);
        a1 = fmaf(wvv, Gl[k*3+1], a1);
        a2 = fmaf(wvv, Gl[k*3+2], a2);
    }
    float* dp = dxr + ((size_t)b * NATOMS + o) * 3;
    dp[0] = a0; dp[1] = a1; dp[2] = a2;
}

// ---------------------------------------------------------------------------
__global__ __launch_bounds__(256)
void cgo_kernel(const float* __restrict__ assign_norm, const float* __restrict__ dxr,
                float* __restrict__ cgo)
{
    __shared__ float dxl[64 * 3];
    const int tid = threadIdx.x;
    const int b   = blockIdx.x >> 4;
    const int a0  = (blockIdx.x & 15) * 64;
    if (tid < 192) dxl[tid] = dxr[((size_t)b * NATOMS + a0) * 3 + tid];
    __syncthreads();
    float c0 = 0.f, c1 = 0.f, c2 = 0.f;
    const float* an = assign_norm + ((size_t)b * NATOMS + a0) * NCGS + tid;
    #pragma unroll 4
    for (int a = 0; a < 64; ++a) {
        float v = an[(size_t)a * NCGS];
        c0 = fmaf(v, dxl[a*3+0], c0);
        c1 = fmaf(v, dxl[a*3+1], c1);
        c2 = fmaf(v, dxl[a*3+2], c2);
    }
    float* cp = cgo + ((size_t)b * NCGS + tid) * 3;
    atomicAdd(cp+0, c0); atomicAdd(cp+1, c1); atomicAdd(cp+2, c2);
}

// ---------------------------------------------------------------------------
__global__ __launch_bounds__(256)
void recon_kernel(const float* __restrict__ cg_xyz, const float* __restrict__ cgo,
                  const float* __restrict__ dxr, const int* __restrict__ assign_idx,
                  float* __restrict__ out)
{
    int i = blockIdx.x * 256 + threadIdx.x;
    int b   = i / (NATOMS * 3);
    int rem = i - b * (NATOMS * 3);
    int a   = rem / 3;
    int n   = rem - a * 3;
    int ia  = assign_idx[a];
    float v = cg_xyz[((size_t)b*NCGS + ia)*3 + n]
            - cgo[((size_t)b*NCGS + ia)*3 + n]
            + dxr[((size_t)b*NATOMS + a)*3 + n];
    out[i] = v;
}

// ---------------------------------------------------------------------------
extern "C" void kernel_launch(void* const* d_in, const int* in_sizes, int n_in,
                              void* d_out, int out_size, void* d_ws, size_t ws_size,
                              hipStream_t stream)
{
    const float* soft_assign = (const float*)d_in[0];
    const float* xyz         = (const float*)d_in[1];
    const float* cg_xyz      = (const float*)d_in[2];
    const float* assign_norm = (const float*)d_in[3];
    const int*   assign_idx  = (const int*)  d_in[4];
    const float* mlp_W1 = (const float*)d_in[5];
    const float* mlp_b1 = (const float*)d_in[6];
    const float* mlp_W2 = (const float*)d_in[7];
    const float* mlp_b2 = (const float*)d_in[8];
    const float* upd_W1 = (const float*)d_in[9];
    const float* upd_b1 = (const float*)d_in[10];
    const float* upd_W2 = (const float*)d_in[11];
    const float* upd_b2 = (const float*)d_in[12];
    const float* dec_W1 = (const float*)d_in[13];
    const float* dec_b1 = (const float*)d_in[14];
    const float* dec_W2 = (const float*)d_in[15];
    const float* dec_b2 = (const float*)d_in[16];

    float* out = (float*)d_out;

    // ws layout: Wswz (832 KB) | G (24 KB) | cgo (48 KB) | dxr (192 KB)
    uint*  Wswz = (uint*)d_ws;
    float* G    = (float*)d_ws + NFRAG*2*64*4;
    float* cgo  = G + BATCH * KF * 3;
    float* dxr  = cgo + BATCH * NCGS * 3;

    hipMemcpyAsync(out, soft_assign, (size_t)BATCH*NATOMS*NCGS*sizeof(float),
                   hipMemcpyDeviceToDevice, stream);
    hipMemcpyAsync(out + (size_t)BATCH*NATOMS*NCGS, xyz,
                   (size_t)BATCH*NATOMS*3*sizeof(float),
                   hipMemcpyDeviceToDevice, stream);
    hipMemsetAsync(G, 0, (size_t)(BATCH*KF*3 + BATCH*NCGS*3)*sizeof(float), stream);

    prep_kernel<<<104, 256, 0, stream>>>(mlp_W1, mlp_W2, upd_W1, upd_W2, dec_W1, Wswz);
    mlp_kernel<<<BATCH*64, 256, 0, stream>>>(cg_xyz, (const bf16x8*)Wswz,
        mlp_b1, mlp_b2, upd_b1, upd_b2, dec_b1, G);
    dx_kernel<<<BATCH*4, 256, 0, stream>>>(cg_xyz, dec_W2, dec_b2, G, dxr);
    cgo_kernel<<<BATCH*16, 256, 0, stream>>>(assign_norm, dxr, cgo);
    recon_kernel<<<(BATCH*NATOMS*3)/256, 256, 0, stream>>>(
        cg_xyz, cgo, dxr, assign_idx,
        out + (size_t)BATCH*NATOMS*NCGS + (size_t)BATCH*NATOMS*3);
}